// Round 9
// baseline (141.445 us; speedup 1.0000x reference)
//
#include <hip/hip_runtime.h>
#include <hip/hip_bf16.h>

typedef __attribute__((ext_vector_type(8))) short short8;
typedef __attribute__((ext_vector_type(4))) float f32x4;

#define PATH_W 0.0625f
#define INV_SQRT3 0.57735026918962576f

typedef const __attribute__((address_space(1))) char gchar;
typedef __attribute__((address_space(3))) char schar;

__device__ __forceinline__ unsigned short f2bf(float f) {
    unsigned int u = __builtin_bit_cast(unsigned int, f);
    u += 0x7FFFu + ((u >> 16) & 1u);   // round-to-nearest-even
    return (unsigned short)(u >> 16);
}

__device__ __forceinline__ float silu(float x) {
    return x / (1.0f + __expf(-x));
}

// ---------------------------------------------------------------------------
// Prep (unchanged): block 0 -> coefficient/constant table; blocks 1..128 ->
// frag-major bf16 weight fragments (W1 standard pack, W2/W3 phi-pack).
// ---------------------------------------------------------------------------
__global__ void prep_all(const float* __restrict__ Wq0, const float* __restrict__ bq,
                         const float* __restrict__ Wv0, const float* __restrict__ bv,
                         const float* __restrict__ Wv1, const float* __restrict__ wq_s,
                         const float* __restrict__ wv_s, const float* __restrict__ wv_v,
                         const float* __restrict__ W1, const float* __restrict__ W2,
                         const float* __restrict__ W3, const float* __restrict__ b1,
                         const float* __restrict__ b2, const float* __restrict__ b3,
                         const float* __restrict__ W4, const float* __restrict__ b4,
                         float* __restrict__ vecs, unsigned short* __restrict__ wp) {
    if (blockIdx.x == 0) {
        int u = threadIdx.x;  // 0..127
        float aq = 0.f, bqs = 0.f, av = 0.f, bvs = 0.f, a1 = 0.f;
        for (int v = 0; v < 128; ++v) {
            float rq = wq_s[u * 128 + v];
            float rv = wv_s[u * 128 + v];
            aq  += Wq0[v] * rq;
            bqs += bq[v]  * rq;
            av  += Wv0[v] * rv;
            bvs += bv[v]  * rv;
            a1  += Wv1[v] * wv_v[u * 128 + v];
        }
        vecs[u]        = PATH_W * aq;
        vecs[128 + u]  = PATH_W * bqs;
        vecs[256 + u]  = PATH_W * av;
        vecs[384 + u]  = PATH_W * bvs;
        vecs[512 + u]  = PATH_W * INV_SQRT3 * a1;
        vecs[640 + u]  = b1[u];
        vecs[768 + u]  = b2[u];
        vecs[896 + u]  = b3[u];
        vecs[1024 + u] = W4[u];
        if (u == 0) { vecs[1152] = b4[0]; vecs[1153] = 0.f; vecs[1154] = 0.f; vecs[1155] = 0.f; }
        return;
    }
    int fid  = blockIdx.x - 1;      // 0..127
    int t    = threadIdx.x;         // 0..127
    int lane = t & 63;
    int half = t >> 6;
    int g  = lane >> 4;
    int r  = lane & 15;
    const float* W;
    int row0, col;
    if (fid < 64) {                       // W1: standard pack
        int mt = fid >> 3, ks = fid & 7;
        W = W1; col = mt * 16 + r;
        row0 = ks * 32 + g * 8 + half * 4;
    } else {                              // W2/W3: phi-pack
        int f2 = fid < 96 ? fid - 64 : fid - 96;
        int mt = f2 >> 2, ks = f2 & 3;
        W = fid < 96 ? W2 : W3; col = mt * 16 + r;
        row0 = half * 64 + ks * 16 + g * 4;
    }
    unsigned short* dst = wp + fid * 512 + lane * 8 + half * 4;
    #pragma unroll
    for (int j = 0; j < 4; ++j) dst[j] = f2bf(W[(row0 + j) * 128 + col]);
}

// ---------------------------------------------------------------------------
// Persistent fused kernel, round 9: 256 threads = 4 waves; LDS cut to
// W1 (64KB) + consts so TWO blocks fit per CU (8 waves/CU = 2/SIMD) --
// doubles memory-level parallelism (round 8 was latency-bound at 1 wave/SIMD,
// achieving only 10 of the 24.6 B/ns per-CU HBM share).
// GEMM2/GEMM3 A-fragments are read per-ks directly from global wp
// (1KB/instr coalesced; 64KB working set -> L2-resident; latency covered by
// the co-resident block). Ring buffer with in-place slot refill retained.
// ---------------------------------------------------------------------------
__global__ __launch_bounds__(256, 1) void fused_main(
    const float* __restrict__ nf,     // node_feats [N,512]
    const float* __restrict__ field,  // field_feats [N,4]
    const float* __restrict__ c0, const float* __restrict__ ci,
    const float* __restrict__ vecs,   // constant table (1156 f32)
    const unsigned short* __restrict__ wp,  // packed bf16 frags (128KB)
    float* __restrict__ out, int N)
{
    __shared__ __align__(16) char smem[65536];
    __shared__ __align__(16) float vlds[1156];
    const int tid  = threadIdx.x;
    const int wave = tid >> 6;      // 0..3
    const int lane = tid & 63;
    const int g    = lane >> 4;     // k-group within frag
    const int nl   = lane & 15;     // node-in-wave == MFMA column
    const int T    = (N + 63) >> 6;
    const char* wpb = (const char*)wp;

    // ---- stage W1 (64KB) into LDS once (16KB per wave) ----
    #pragma unroll
    for (int i = 0; i < 16; ++i) {
        int off = (wave * 16 + i) * 1024;
        __builtin_amdgcn_global_load_lds((gchar*)(wpb + off + lane * 16),
                                         (schar*)(smem + off), 16, 0, 0);
    }
    // ---- constant table -> LDS (wave 0) ----
    if (wave == 0) {
        #pragma unroll
        for (int i = 0; i < 5; ++i) {
            int idx = lane + 64 * i;
            if (idx < 289)
                reinterpret_cast<f32x4*>(vlds)[idx] =
                    reinterpret_cast<const f32x4*>(vecs)[idx];
        }
    }

    // ring buffer: 8 half-quarter slots x (s 16B + v 48B) = 512B/lane
    f32x4 hs[8], hv0[8], hv1[8], hv2[8];
    float c0r, cir; f32x4 ffr;

#define SLOT_LOAD(hh_, bs_, bv_) {                                            \
        const int q_ = (hh_) >> 1, h_ = (hh_) & 1;                            \
        hs[hh_]  = *reinterpret_cast<const f32x4*>((bs_) + 128 * q_ + 16 * h_); \
        hv0[hh_] = *reinterpret_cast<const f32x4*>((bv_) + 384 * q_ + 48 * h_); \
        hv1[hh_] = *reinterpret_cast<const f32x4*>((bv_) + 384 * q_ + 48 * h_ + 16); \
        hv2[hh_] = *reinterpret_cast<const f32x4*>((bv_) + 384 * q_ + 48 * h_ + 32); }

    int tile = blockIdx.x;
    {   // prologue: load full tile 0 + scalars
        int nd0 = tile * 64 + wave * 16 + nl;
        int ndc = nd0 < N ? nd0 : N - 1;
        const char* nrow = (const char*)nf + (size_t)ndc * 2048;
        const char* bs0 = nrow + 32 * g;
        const char* bv0 = nrow + 512 + 96 * g;
        #pragma unroll
        for (int hh = 0; hh < 8; ++hh) SLOT_LOAD(hh, bs0, bv0)
        c0r = c0[ndc]; cir = ci[ndc];
        ffr = reinterpret_cast<const f32x4*>(field)[ndc];
    }

    __syncthreads();   // W1 + constants resident

    const f32x4* vl4 = reinterpret_cast<const f32x4*>(vlds);

    for (; tile < T; tile += gridDim.x) {
        const int nd = tile * 64 + wave * 16 + nl;
        const int nt = tile + gridDim.x;
        const bool hasnext = nt < T;

        // next-tile bases + scalar prefetch (block-uniform branch)
        const char* bsn = nullptr; const char* bvn = nullptr;
        float c0n = 0.f, cin = 0.f; f32x4 ffn = ffr;
        if (hasnext) {
            int ndn = nt * 64 + wave * 16 + nl;
            ndn = ndn < N ? ndn : N - 1;
            const char* nrow = (const char*)nf + (size_t)ndn * 2048;
            bsn = nrow + 32 * g;
            bvn = nrow + 512 + 96 * g;
            c0n = c0[ndn]; cin = ci[ndn];
            ffn = reinterpret_cast<const f32x4*>(field)[ndn];
        }

        const float q_in = c0r + cir;
        const f32x4 ff   = ffr;

        // ---- GEMM1 (K=256): per-quarter h-compute + MFMA, in-place refill ----
        f32x4 acc[8];
        #pragma unroll
        for (int mt = 0; mt < 8; ++mt) acc[mt] = vl4[160 + mt * 4 + g];   // b1

        short8 hfA, hfB;
        #pragma unroll
        for (int q = 0; q < 4; ++q) {
            #pragma unroll
            for (int h = 0; h < 2; ++h) {
                const int hh = 2 * q + h;
                const int m  = 8 * q + 2 * g + h;
                f32x4 aq = vl4[m], bqv = vl4[32 + m], av = vl4[64 + m],
                      bvv = vl4[96 + m], a1 = vl4[128 + m];
                f32x4 s = hs[hh], va = hv0[hh], vb = hv1[hh], vc = hv2[hh];
                float d3[4];
                d3[0] = fmaf(va[0], ff[1], fmaf(va[1], ff[2], va[2] * ff[3]));
                d3[1] = fmaf(va[3], ff[1], fmaf(vb[0], ff[2], vb[1] * ff[3]));
                d3[2] = fmaf(vb[2], ff[1], fmaf(vb[3], ff[2], vc[0] * ff[3]));
                d3[3] = fmaf(vc[1], ff[1], fmaf(vc[2], ff[2], vc[3] * ff[3]));
                #pragma unroll
                for (int j = 0; j < 4; ++j) {
                    float hq = s[j] * fmaf(q_in, aq[j], bqv[j]);
                    float hv = fmaf(s[j], fmaf(ff[0], av[j], bvv[j]), a1[j] * d3[j]);
                    if (h == 0) { hfA[j]     = (short)f2bf(hq); hfB[j]     = (short)f2bf(hv); }
                    else        { hfA[4 + j] = (short)f2bf(hq); hfB[4 + j] = (short)f2bf(hv); }
                }
                // pin: slot hh fully consumed above; refill may not hoist past this
                __builtin_amdgcn_sched_barrier(0);
                if (hasnext) SLOT_LOAD(hh, bsn, bvn)
            }
            // quarter q complete: 16 MFMA (ks=q with hfA, ks=q+4 with hfB)
            #pragma unroll
            for (int mt = 0; mt < 8; ++mt) {
                short8 a0 = *reinterpret_cast<const short8*>(
                    smem + (mt * 8 + q) * 1024 + lane * 16);
                acc[mt] = __builtin_amdgcn_mfma_f32_16x16x32_bf16(a0, hfA, acc[mt], 0, 0, 0);
                short8 a4 = *reinterpret_cast<const short8*>(
                    smem + (mt * 8 + q + 4) * 1024 + lane * 16);
                acc[mt] = __builtin_amdgcn_mfma_f32_16x16x32_bf16(a4, hfB, acc[mt], 0, 0, 0);
            }
        }

        // ---- repack (phi) -> GEMM2 (K=128, 32 MFMA), A-frags from L2 ----
        short8 hf2[4];
        #pragma unroll
        for (int ks = 0; ks < 4; ++ks)
            #pragma unroll
            for (int hp = 0; hp < 2; ++hp)
                #pragma unroll
                for (int j = 0; j < 4; ++j)
                    hf2[ks][hp * 4 + j] = (short)f2bf(silu(acc[hp * 4 + ks][j]));

        f32x4 acc2[8];
        #pragma unroll
        for (int mt = 0; mt < 8; ++mt) acc2[mt] = vl4[192 + mt * 4 + g];  // b2
        #pragma unroll
        for (int ks = 0; ks < 4; ++ks) {
            #pragma unroll
            for (int mt = 0; mt < 8; ++mt) {
                short8 a = *reinterpret_cast<const short8*>(
                    wpb + 65536 + (mt * 4 + ks) * 1024 + lane * 16);
                acc2[mt] = __builtin_amdgcn_mfma_f32_16x16x32_bf16(a, hf2[ks], acc2[mt], 0, 0, 0);
            }
        }

        // ---- repack -> GEMM3 (K=128, 32 MFMA), A-frags from L2 ----
        short8 hf3[4];
        #pragma unroll
        for (int ks = 0; ks < 4; ++ks)
            #pragma unroll
            for (int hp = 0; hp < 2; ++hp)
                #pragma unroll
                for (int j = 0; j < 4; ++j)
                    hf3[ks][hp * 4 + j] = (short)f2bf(silu(acc2[hp * 4 + ks][j]));

        f32x4 acc3[8];
        #pragma unroll
        for (int mt = 0; mt < 8; ++mt) acc3[mt] = vl4[224 + mt * 4 + g];  // b3
        #pragma unroll
        for (int ks = 0; ks < 4; ++ks) {
            #pragma unroll
            for (int mt = 0; mt < 8; ++mt) {
                short8 a = *reinterpret_cast<const short8*>(
                    wpb + 98304 + (mt * 4 + ks) * 1024 + lane * 16);
                acc3[mt] = __builtin_amdgcn_mfma_f32_16x16x32_bf16(a, hf3[ks], acc3[mt], 0, 0, 0);
            }
        }

        // ---- epilogue: out[n] = silu(h3) . W4 + b4 ----
        float acc_out = 0.f;
        #pragma unroll
        for (int mt = 0; mt < 8; ++mt) {
            f32x4 w4v = vl4[256 + mt * 4 + g];
            acc_out += silu(acc3[mt][0]) * w4v[0];
            acc_out += silu(acc3[mt][1]) * w4v[1];
            acc_out += silu(acc3[mt][2]) * w4v[2];
            acc_out += silu(acc3[mt][3]) * w4v[3];
        }
        acc_out += __shfl_xor(acc_out, 16, 64);
        acc_out += __shfl_xor(acc_out, 32, 64);
        if (g == 0 && nd < N) out[nd] = acc_out + vlds[1152];

        // advance scalars to next tile
        c0r = c0n; cir = cin; ffr = ffn;
    }
#undef SLOT_LOAD
}

extern "C" void kernel_launch(void* const* d_in, const int* in_sizes, int n_in,
                              void* d_out, int out_size, void* d_ws, size_t ws_size,
                              hipStream_t stream) {
    const float* node_feats = (const float*)d_in[1];
    const float* field      = (const float*)d_in[5];
    const float* c0         = (const float*)d_in[6];
    const float* ci         = (const float*)d_in[7];
    const float* Wq0        = (const float*)d_in[8];
    const float* bq         = (const float*)d_in[9];
    const float* Wv0        = (const float*)d_in[10];
    const float* bv         = (const float*)d_in[11];
    const float* Wv1        = (const float*)d_in[12];
    const float* wq_s       = (const float*)d_in[13];
    // d_in[14] = wq_v multiplies q_up_v == 0 -> unused
    const float* wv_s       = (const float*)d_in[15];
    const float* wv_v       = (const float*)d_in[16];
    const float* W1         = (const float*)d_in[17];
    const float* b1         = (const float*)d_in[18];
    const float* W2         = (const float*)d_in[19];
    const float* b2         = (const float*)d_in[20];
    const float* W3         = (const float*)d_in[21];
    const float* b3         = (const float*)d_in[22];
    const float* W4         = (const float*)d_in[23];
    const float* b4         = (const float*)d_in[24];

    const int N = in_sizes[1] / 512;           // node_feats is [N, 4*C]
    float* vecs = (float*)d_ws;                 // 1156 f32 constant table
    unsigned short* wp = (unsigned short*)((char*)d_ws + 8192);  // 128 frags x 1KB

    prep_all<<<129, 128, 0, stream>>>(Wq0, bq, Wv0, bv, Wv1, wq_s, wv_s, wv_v,
                                      W1, W2, W3, b1, b2, b3, W4, b4, vecs, wp);
    const int T = (N + 63) / 64;
    const int blocks = T < 512 ? T : 512;
    fused_main<<<blocks, 256, 0, stream>>>(node_feats, field, c0, ci, vecs, wp,
                                           (float*)d_out, N);
}

// Round 10
// 73.981 us; speedup vs baseline: 1.9119x; 1.9119x over previous
//
#include <hip/hip_runtime.h>
#include <hip/hip_bf16.h>

typedef __attribute__((ext_vector_type(8))) short short8;
typedef __attribute__((ext_vector_type(4))) float f32x4;

#define PATH_W 0.0625f
#define INV_SQRT3 0.57735026918962576f

typedef const __attribute__((address_space(1))) char gchar;
typedef __attribute__((address_space(3))) char schar;

__device__ __forceinline__ unsigned short f2bf(float f) {
    unsigned int u = __builtin_bit_cast(unsigned int, f);
    u += 0x7FFFu + ((u >> 16) & 1u);   // round-to-nearest-even
    return (unsigned short)(u >> 16);
}

__device__ __forceinline__ float silu(float x) {
    return x / (1.0f + __expf(-x));
}

// ---------------------------------------------------------------------------
// Prep (unchanged): block 0 -> coefficient/constant table; blocks 1..128 ->
// frag-major bf16 weight fragments (W1 standard pack, W2/W3 phi-pack).
// ---------------------------------------------------------------------------
__global__ void prep_all(const float* __restrict__ Wq0, const float* __restrict__ bq,
                         const float* __restrict__ Wv0, const float* __restrict__ bv,
                         const float* __restrict__ Wv1, const float* __restrict__ wq_s,
                         const float* __restrict__ wv_s, const float* __restrict__ wv_v,
                         const float* __restrict__ W1, const float* __restrict__ W2,
                         const float* __restrict__ W3, const float* __restrict__ b1,
                         const float* __restrict__ b2, const float* __restrict__ b3,
                         const float* __restrict__ W4, const float* __restrict__ b4,
                         float* __restrict__ vecs, unsigned short* __restrict__ wp) {
    if (blockIdx.x == 0) {
        int u = threadIdx.x;  // 0..127
        float aq = 0.f, bqs = 0.f, av = 0.f, bvs = 0.f, a1 = 0.f;
        for (int v = 0; v < 128; ++v) {
            float rq = wq_s[u * 128 + v];
            float rv = wv_s[u * 128 + v];
            aq  += Wq0[v] * rq;
            bqs += bq[v]  * rq;
            av  += Wv0[v] * rv;
            bvs += bv[v]  * rv;
            a1  += Wv1[v] * wv_v[u * 128 + v];
        }
        vecs[u]        = PATH_W * aq;
        vecs[128 + u]  = PATH_W * bqs;
        vecs[256 + u]  = PATH_W * av;
        vecs[384 + u]  = PATH_W * bvs;
        vecs[512 + u]  = PATH_W * INV_SQRT3 * a1;
        vecs[640 + u]  = b1[u];
        vecs[768 + u]  = b2[u];
        vecs[896 + u]  = b3[u];
        vecs[1024 + u] = W4[u];
        if (u == 0) { vecs[1152] = b4[0]; vecs[1153] = 0.f; vecs[1154] = 0.f; vecs[1155] = 0.f; }
        return;
    }
    int fid  = blockIdx.x - 1;      // 0..127
    int t    = threadIdx.x;         // 0..127
    int lane = t & 63;
    int half = t >> 6;
    int g  = lane >> 4;
    int r  = lane & 15;
    const float* W;
    int row0, col;
    if (fid < 64) {                       // W1: standard pack
        int mt = fid >> 3, ks = fid & 7;
        W = W1; col = mt * 16 + r;
        row0 = ks * 32 + g * 8 + half * 4;
    } else {                              // W2/W3: phi-pack
        int f2 = fid < 96 ? fid - 64 : fid - 96;
        int mt = f2 >> 2, ks = f2 & 3;
        W = fid < 96 ? W2 : W3; col = mt * 16 + r;
        row0 = half * 64 + ks * 16 + g * 4;
    }
    unsigned short* dst = wp + fid * 512 + lane * 8 + half * 4;
    #pragma unroll
    for (int j = 0; j < 4; ++j) dst[j] = f2bf(W[(row0 + j) * 128 + col]);
}

// ---------------------------------------------------------------------------
// Persistent fused kernel, round 10: 512 threads = 8 waves (2/SIMD for TLP),
// ALL weights in LDS (136KB -> 1 block/CU). Per-wave register buffer is a
// HALF tile (4 slots = 64 VGPRs) so the 8-wave 128-VGPR budget holds:
//   half 0: consume k01 (loaded last phase), refill k23 of CURRENT tile
//   half 1: consume k23,                    refill k01 of NEXT tile
// In-place slot refill + sched_barrier(0) pinning (round 8's no-spill trick).
// GEMM2/3 A-frags from LDS (round 9's global reads poisoned the vmcnt FIFO).
// ---------------------------------------------------------------------------
__global__ __launch_bounds__(512, 1) void fused_main(
    const float* __restrict__ nf,     // node_feats [N,512]
    const float* __restrict__ field,  // field_feats [N,4]
    const float* __restrict__ c0, const float* __restrict__ ci,
    const float* __restrict__ vecs,   // constant table (1156 f32)
    const unsigned short* __restrict__ wp,  // packed bf16 frags (128KB)
    float* __restrict__ out, int N)
{
    __shared__ __align__(16) char smem[131072];
    __shared__ __align__(16) float vlds[1156];
    const int tid  = threadIdx.x;
    const int wave = tid >> 6;      // 0..7
    const int lane = tid & 63;
    const int g    = lane >> 4;     // k-group within frag
    const int nl   = lane & 15;     // node-in-wave == MFMA column
    const int T    = (N + 127) >> 7;   // 128-node tiles
    const char* wpb = (const char*)wp;

    // ---- stage ALL weights (128KB) into LDS once (16KB per wave) ----
    #pragma unroll
    for (int i = 0; i < 16; ++i) {
        int off = (wave * 16 + i) * 1024;
        __builtin_amdgcn_global_load_lds((gchar*)(wpb + off + lane * 16),
                                         (schar*)(smem + off), 16, 0, 0);
    }
    // ---- constant table -> LDS (wave 0) ----
    if (wave == 0) {
        #pragma unroll
        for (int i = 0; i < 5; ++i) {
            int idx = lane + 64 * i;
            if (idx < 289)
                reinterpret_cast<f32x4*>(vlds)[idx] =
                    reinterpret_cast<const f32x4*>(vecs)[idx];
        }
    }

    // half-tile ring: 4 slots x (s 16B + v 48B) = 256B/lane = 64 VGPRs
    f32x4 hs[4], hv0[4], hv1[4], hv2[4];
    float c0r, cir; f32x4 ffr;
    const char* bsr; const char* bvr;   // current-tile bases

#define SLOT_LOAD(sl_, q_, h_, bs_, bv_) {                                    \
        hs[sl_]  = *reinterpret_cast<const f32x4*>((bs_) + 128 * (q_) + 16 * (h_)); \
        hv0[sl_] = *reinterpret_cast<const f32x4*>((bv_) + 384 * (q_) + 48 * (h_)); \
        hv1[sl_] = *reinterpret_cast<const f32x4*>((bv_) + 384 * (q_) + 48 * (h_) + 16); \
        hv2[sl_] = *reinterpret_cast<const f32x4*>((bv_) + 384 * (q_) + 48 * (h_) + 32); }

    int tile = blockIdx.x;
    {   // prologue: load k01 half of tile 0 + scalars
        int nd0 = tile * 128 + wave * 16 + nl;
        int ndc = nd0 < N ? nd0 : N - 1;
        const char* nrow = (const char*)nf + (size_t)ndc * 2048;
        bsr = nrow + 32 * g;
        bvr = nrow + 512 + 96 * g;
        #pragma unroll
        for (int qh = 0; qh < 2; ++qh)
            #pragma unroll
            for (int h = 0; h < 2; ++h)
                SLOT_LOAD(2 * qh + h, qh, h, bsr, bvr)
        c0r = c0[ndc]; cir = ci[ndc];
        ffr = reinterpret_cast<const f32x4*>(field)[ndc];
    }

    __syncthreads();   // weights + constants resident

    const f32x4* vl4 = reinterpret_cast<const f32x4*>(vlds);

    for (; tile < T; tile += gridDim.x) {
        const int nd = tile * 128 + wave * 16 + nl;
        const int nt = tile + gridDim.x;
        const bool hasnext = nt < T;

        // next-tile bases + scalar prefetch
        const char* bsn = bsr; const char* bvn = bvr;
        float c0n = 0.f, cin = 0.f; f32x4 ffn = ffr;
        if (hasnext) {
            int ndn = nt * 128 + wave * 16 + nl;
            ndn = ndn < N ? ndn : N - 1;
            const char* nrow = (const char*)nf + (size_t)ndn * 2048;
            bsn = nrow + 32 * g;
            bvn = nrow + 512 + 96 * g;
            c0n = c0[ndn]; cin = ci[ndn];
            ffn = reinterpret_cast<const f32x4*>(field)[ndn];
        }

        const float q_in = c0r + cir;
        const f32x4 ff   = ffr;

        // ---- GEMM1 (K=256): two halves x two quarters, in-place refill ----
        f32x4 acc[8];
        #pragma unroll
        for (int mt = 0; mt < 8; ++mt) acc[mt] = vl4[160 + mt * 4 + g];   // b1

        short8 hfA, hfB;
        #pragma unroll
        for (int half = 0; half < 2; ++half) {
            #pragma unroll
            for (int qh = 0; qh < 2; ++qh) {
                const int q = 2 * half + qh;
                #pragma unroll
                for (int h = 0; h < 2; ++h) {
                    const int slot = 2 * qh + h;
                    const int m = 8 * q + 2 * g + h;
                    f32x4 aq = vl4[m], bqv = vl4[32 + m], av = vl4[64 + m],
                          bvv = vl4[96 + m], a1 = vl4[128 + m];
                    f32x4 s = hs[slot], va = hv0[slot], vb = hv1[slot], vc = hv2[slot];
                    float d3[4];
                    d3[0] = fmaf(va[0], ff[1], fmaf(va[1], ff[2], va[2] * ff[3]));
                    d3[1] = fmaf(va[3], ff[1], fmaf(vb[0], ff[2], vb[1] * ff[3]));
                    d3[2] = fmaf(vb[2], ff[1], fmaf(vb[3], ff[2], vc[0] * ff[3]));
                    d3[3] = fmaf(vc[1], ff[1], fmaf(vc[2], ff[2], vc[3] * ff[3]));
                    #pragma unroll
                    for (int j = 0; j < 4; ++j) {
                        float hq = s[j] * fmaf(q_in, aq[j], bqv[j]);
                        float hv = fmaf(s[j], fmaf(ff[0], av[j], bvv[j]), a1[j] * d3[j]);
                        if (h == 0) { hfA[j]     = (short)f2bf(hq); hfB[j]     = (short)f2bf(hv); }
                        else        { hfA[4 + j] = (short)f2bf(hq); hfB[4 + j] = (short)f2bf(hv); }
                    }
                    // pin: slot consumed above; refill must not hoist past this
                    __builtin_amdgcn_sched_barrier(0);
                    if (half == 0) {
                        SLOT_LOAD(slot, qh + 2, h, bsr, bvr)       // current tile k23
                    } else if (hasnext) {
                        SLOT_LOAD(slot, qh, h, bsn, bvn)           // next tile k01
                    }
                }
                // quarter q complete: 16 MFMA (ks=q with hfA, ks=q+4 with hfB)
                #pragma unroll
                for (int mt = 0; mt < 8; ++mt) {
                    short8 a0 = *reinterpret_cast<const short8*>(
                        smem + (mt * 8 + q) * 1024 + lane * 16);
                    acc[mt] = __builtin_amdgcn_mfma_f32_16x16x32_bf16(a0, hfA, acc[mt], 0, 0, 0);
                    short8 a4 = *reinterpret_cast<const short8*>(
                        smem + (mt * 8 + q + 4) * 1024 + lane * 16);
                    acc[mt] = __builtin_amdgcn_mfma_f32_16x16x32_bf16(a4, hfB, acc[mt], 0, 0, 0);
                }
            }
        }

        // ---- repack (phi) -> GEMM2 (K=128, 32 MFMA) ----
        short8 hf2[4];
        #pragma unroll
        for (int ks = 0; ks < 4; ++ks)
            #pragma unroll
            for (int hp = 0; hp < 2; ++hp)
                #pragma unroll
                for (int j = 0; j < 4; ++j)
                    hf2[ks][hp * 4 + j] = (short)f2bf(silu(acc[hp * 4 + ks][j]));

        f32x4 acc2[8];
        #pragma unroll
        for (int mt = 0; mt < 8; ++mt) acc2[mt] = vl4[192 + mt * 4 + g];  // b2
        #pragma unroll
        for (int ks = 0; ks < 4; ++ks) {
            #pragma unroll
            for (int mt = 0; mt < 8; ++mt) {
                short8 a = *reinterpret_cast<const short8*>(
                    smem + 65536 + (mt * 4 + ks) * 1024 + lane * 16);
                acc2[mt] = __builtin_amdgcn_mfma_f32_16x16x32_bf16(a, hf2[ks], acc2[mt], 0, 0, 0);
            }
        }

        // ---- repack -> GEMM3 (K=128, 32 MFMA) ----
        short8 hf3[4];
        #pragma unroll
        for (int ks = 0; ks < 4; ++ks)
            #pragma unroll
            for (int hp = 0; hp < 2; ++hp)
                #pragma unroll
                for (int j = 0; j < 4; ++j)
                    hf3[ks][hp * 4 + j] = (short)f2bf(silu(acc2[hp * 4 + ks][j]));

        f32x4 acc3[8];
        #pragma unroll
        for (int mt = 0; mt < 8; ++mt) acc3[mt] = vl4[224 + mt * 4 + g];  // b3
        #pragma unroll
        for (int ks = 0; ks < 4; ++ks) {
            #pragma unroll
            for (int mt = 0; mt < 8; ++mt) {
                short8 a = *reinterpret_cast<const short8*>(
                    smem + 98304 + (mt * 4 + ks) * 1024 + lane * 16);
                acc3[mt] = __builtin_amdgcn_mfma_f32_16x16x32_bf16(a, hf3[ks], acc3[mt], 0, 0, 0);
            }
        }

        // ---- epilogue: out[n] = silu(h3) . W4 + b4 ----
        float acc_out = 0.f;
        #pragma unroll
        for (int mt = 0; mt < 8; ++mt) {
            f32x4 w4v = vl4[256 + mt * 4 + g];
            acc_out += silu(acc3[mt][0]) * w4v[0];
            acc_out += silu(acc3[mt][1]) * w4v[1];
            acc_out += silu(acc3[mt][2]) * w4v[2];
            acc_out += silu(acc3[mt][3]) * w4v[3];
        }
        acc_out += __shfl_xor(acc_out, 16, 64);
        acc_out += __shfl_xor(acc_out, 32, 64);
        if (g == 0 && nd < N) out[nd] = acc_out + vlds[1152];

        // advance to next tile
        bsr = bsn; bvr = bvn;
        c0r = c0n; cir = cin; ffr = ffn;
    }
#undef SLOT_LOAD
}

extern "C" void kernel_launch(void* const* d_in, const int* in_sizes, int n_in,
                              void* d_out, int out_size, void* d_ws, size_t ws_size,
                              hipStream_t stream) {
    const float* node_feats = (const float*)d_in[1];
    const float* field      = (const float*)d_in[5];
    const float* c0         = (const float*)d_in[6];
    const float* ci         = (const float*)d_in[7];
    const float* Wq0        = (const float*)d_in[8];
    const float* bq         = (const float*)d_in[9];
    const float* Wv0        = (const float*)d_in[10];
    const float* bv         = (const float*)d_in[11];
    const float* Wv1        = (const float*)d_in[12];
    const float* wq_s       = (const float*)d_in[13];
    // d_in[14] = wq_v multiplies q_up_v == 0 -> unused
    const float* wv_s       = (const float*)d_in[15];
    const float* wv_v       = (const float*)d_in[16];
    const float* W1         = (const float*)d_in[17];
    const float* b1         = (const float*)d_in[18];
    const float* W2         = (const float*)d_in[19];
    const float* b2         = (const float*)d_in[20];
    const float* W3         = (const float*)d_in[21];
    const float* b3         = (const float*)d_in[22];
    const float* W4         = (const float*)d_in[23];
    const float* b4         = (const float*)d_in[24];

    const int N = in_sizes[1] / 512;           // node_feats is [N, 4*C]
    float* vecs = (float*)d_ws;                 // 1156 f32 constant table
    unsigned short* wp = (unsigned short*)((char*)d_ws + 8192);  // 128 frags x 1KB

    prep_all<<<129, 128, 0, stream>>>(Wq0, bq, Wv0, bv, Wv1, wq_s, wv_s, wv_v,
                                      W1, W2, W3, b1, b2, b3, W4, b4, vecs, wp);
    const int T = (N + 127) / 128;
    const int blocks = T < 256 ? T : 256;
    fused_main<<<blocks, 512, 0, stream>>>(node_feats, field, c0, ci, vecs, wp,
                                           (float*)d_out, N);
}